// Round 2
// baseline (2830.290 us; speedup 1.0000x reference)
//
#include <hip/hip_runtime.h>

// Trilinear forward-splat: out[clamped corners] += src * trilinear weights.
// H=W=D=192, fp32. Exact reference semantics:
//   locs = max(grid + flow, 0)
//   delta = locs - floor(locs)          (from UNclamped floor)
//   base  = min((int)floor(locs), dim-1)
//   corner index per axis = min(base + {0,1}, dim-1)   (collapsed corners add twice)

constexpr int H = 192, W = 192, Dd = 192;
constexpr int N = H * W * Dd;
constexpr int WD = W * Dd;

__global__ __launch_bounds__(256) void splat4_kernel(const float* __restrict__ src,
                                                     const float* __restrict__ flow,
                                                     float* __restrict__ out) {
    const int t = blockIdx.x * blockDim.x + threadIdx.x;
    const int n0 = t << 2;            // 4 consecutive voxels along D
    if (n0 >= N) return;

    const int i   = n0 / WD;
    const int rem = n0 - i * WD;
    const int j   = rem / Dd;
    const int k0  = rem - j * Dd;     // multiple of 4 (D % 4 == 0)

    const float4 s4  = *reinterpret_cast<const float4*>(src + n0);
    const float4 fx4 = *reinterpret_cast<const float4*>(flow + n0);
    const float4 fy4 = *reinterpret_cast<const float4*>(flow + N + n0);
    const float4 fz4 = *reinterpret_cast<const float4*>(flow + 2 * N + n0);

    const float sa[4]  = {s4.x, s4.y, s4.z, s4.w};
    const float fxa[4] = {fx4.x, fx4.y, fx4.z, fx4.w};
    const float fya[4] = {fy4.x, fy4.y, fy4.z, fy4.w};
    const float fza[4] = {fz4.x, fz4.y, fz4.z, fz4.w};

#pragma unroll
    for (int q = 0; q < 4; ++q) {
        // locs = where(grid+flow > 0, grid+flow, 0)
        const float lx = fmaxf((float)i        + fxa[q], 0.0f);
        const float ly = fmaxf((float)j        + fya[q], 0.0f);
        const float lz = fmaxf((float)(k0 + q) + fza[q], 0.0f);

        const float bx = floorf(lx), by = floorf(ly), bz = floorf(lz);
        const float dx = lx - bx,    dy = ly - by,    dz = lz - bz;

        const int x0 = min((int)bx, H - 1);
        const int y0 = min((int)by, W - 1);
        const int z0 = min((int)bz, Dd - 1);
        const int x1 = min(x0 + 1, H - 1);
        const int y1 = min(y0 + 1, W - 1);
        const int z1 = min(z0 + 1, Dd - 1);

        const float s = sa[q];
        const float wx0 = 1.0f - dx, wx1 = dx;
        const float wy0 = 1.0f - dy, wy1 = dy;
        const float wz0 = 1.0f - dz, wz1 = dz;

        // Pre-multiplied xy weights
        const float a00 = s * wx0 * wy0;
        const float a01 = s * wx0 * wy1;
        const float a10 = s * wx1 * wy0;
        const float a11 = s * wx1 * wy1;

        float* r00 = out + (x0 * W + y0) * Dd;
        float* r01 = out + (x0 * W + y1) * Dd;
        float* r10 = out + (x1 * W + y0) * Dd;
        float* r11 = out + (x1 * W + y1) * Dd;

        unsafeAtomicAdd(r00 + z0, a00 * wz0);
        unsafeAtomicAdd(r00 + z1, a00 * wz1);
        unsafeAtomicAdd(r01 + z0, a01 * wz0);
        unsafeAtomicAdd(r01 + z1, a01 * wz1);
        unsafeAtomicAdd(r10 + z0, a10 * wz0);
        unsafeAtomicAdd(r10 + z1, a10 * wz1);
        unsafeAtomicAdd(r11 + z0, a11 * wz0);
        unsafeAtomicAdd(r11 + z1, a11 * wz1);
    }
}

extern "C" void kernel_launch(void* const* d_in, const int* in_sizes, int n_in,
                              void* d_out, int out_size, void* d_ws, size_t ws_size,
                              hipStream_t stream) {
    const float* src  = (const float*)d_in[0];
    const float* flow = (const float*)d_in[1];
    float* out = (float*)d_out;

    // Harness poisons d_out once and never re-poisons between replays: zero it every call.
    hipMemsetAsync(out, 0, (size_t)N * sizeof(float), stream);

    const int threads = N / 4;                 // 1,769,472
    const dim3 block(256);
    const dim3 grid((threads + 255) / 256);    // 6912 blocks
    splat4_kernel<<<grid, block, 0, stream>>>(src, flow, out);
}

// Round 3
// 316.573 us; speedup vs baseline: 8.9404x; 8.9404x over previous
//
#include <hip/hip_runtime.h>

// Trilinear forward-splat with per-block LDS tile accumulation.
// Reference semantics (exact):
//   locs = max(grid + flow, 0)
//   delta = locs - floor(locs)           (from UNclamped floor)
//   base  = min((int)floor(locs), dim-1)
//   corner per axis = min(base + {0,1}, dim-1)   (collapsed corners add twice)
//
// Block owns an 8x8x64 source chunk; scatters into an LDS tile covering the
// chunk + 4-cell halo (16x16x72 = 73.7KB, 2 blocks/CU). Flow ~ N(0,1) so
// nearly all corners are in-halo; rare outliers use direct global atomics.
// Flush: one coalesced global atomic per nonzero tile cell.

constexpr int H = 192, W = 192, Dd = 192;
constexpr int N = H * W * Dd;
constexpr int WD = W * Dd;

constexpr int BI = 8, BJ = 8, BK = 64;       // source chunk per block
constexpr int HL = 4;                        // halo radius
constexpr int TI = BI + 2 * HL;              // 16
constexpr int TJ = BJ + 2 * HL;              // 16
constexpr int TK = BK + 2 * HL;              // 72
constexpr int TCELLS = TI * TJ * TK;         // 18432 floats = 73.7 KB

// 512 threads/block; 2 blocks/CU wanted -> min 4 waves/SIMD.
__global__ __launch_bounds__(512, 4) void splat_lds_kernel(const float* __restrict__ src,
                                                           const float* __restrict__ flow,
                                                           float* __restrict__ out) {
    __shared__ __align__(16) float tile[TCELLS];

    const int t  = threadIdx.x;
    const int bk = blockIdx.x, bj = blockIdx.y, bi = blockIdx.z;
    const int i0 = bi * BI, j0 = bj * BJ, k0 = bk * BK;
    const int xg0 = i0 - HL, yg0 = j0 - HL, zg0 = k0 - HL;  // tile origin (global)

    // --- zero the tile (4608 float4 / 512 threads = 9 each) ---
    {
        const float4 z4 = make_float4(0.f, 0.f, 0.f, 0.f);
        float4* t4 = reinterpret_cast<float4*>(tile);
#pragma unroll
        for (int r = 0; r < TCELLS / 4 / 512; ++r) t4[t + 512 * r] = z4;
    }
    __syncthreads();

    // --- scatter: 4096 voxels / block, 4 consecutive-k voxels per thread-pass ---
#pragma unroll
    for (int p = 0; p < 2; ++p) {
        const int g  = p * 512 + t;            // float4-group index, 0..1023
        const int kg = (g & 15) * 4;           // 0..60
        const int cj = (g >> 4) & 7;
        const int ci = g >> 7;                 // 0..7
        const int i = i0 + ci, j = j0 + cj, k = k0 + kg;
        const int off = i * WD + j * Dd + k;

        const float4 s4  = *reinterpret_cast<const float4*>(src + off);
        const float4 fx4 = *reinterpret_cast<const float4*>(flow + off);
        const float4 fy4 = *reinterpret_cast<const float4*>(flow + N + off);
        const float4 fz4 = *reinterpret_cast<const float4*>(flow + 2 * N + off);

        const float sa[4]  = {s4.x, s4.y, s4.z, s4.w};
        const float fxa[4] = {fx4.x, fx4.y, fx4.z, fx4.w};
        const float fya[4] = {fy4.x, fy4.y, fy4.z, fy4.w};
        const float fza[4] = {fz4.x, fz4.y, fz4.z, fz4.w};

#pragma unroll
        for (int q = 0; q < 4; ++q) {
            const float lx = fmaxf((float)i       + fxa[q], 0.0f);
            const float ly = fmaxf((float)j       + fya[q], 0.0f);
            const float lz = fmaxf((float)(k + q) + fza[q], 0.0f);

            const float bx = floorf(lx), by = floorf(ly), bz = floorf(lz);
            const float dx = lx - bx,    dy = ly - by,    dz = lz - bz;

            const int x0 = min((int)bx, H - 1);
            const int y0 = min((int)by, W - 1);
            const int z0 = min((int)bz, Dd - 1);
            const int x1 = min(x0 + 1, H - 1);
            const int y1 = min(y0 + 1, W - 1);
            const int z1 = min(z0 + 1, Dd - 1);

            const float s = sa[q];
            const float wx0 = 1.0f - dx, wy0 = 1.0f - dy, wz0 = 1.0f - dz;
            const float a00 = s * wx0 * wy0;
            const float a01 = s * wx0 * dy;
            const float a10 = s * dx * wy0;
            const float a11 = s * dx * dy;

            const float v000 = a00 * wz0, v001 = a00 * dz;
            const float v010 = a01 * wz0, v011 = a01 * dz;
            const float v100 = a10 * wz0, v101 = a10 * dz;
            const float v110 = a11 * wz0, v111 = a11 * dz;

            // tile-local coords
            const int a0 = x0 - xg0, a1 = x1 - xg0;
            const int b0 = y0 - yg0, b1 = y1 - yg0;
            const int c0 = z0 - zg0, c1 = z1 - zg0;

            const bool fast = ((unsigned)a0 < (unsigned)TI) & ((unsigned)a1 < (unsigned)TI) &
                              ((unsigned)b0 < (unsigned)TJ) & ((unsigned)b1 < (unsigned)TJ) &
                              ((unsigned)c0 < (unsigned)TK) & ((unsigned)c1 < (unsigned)TK);

            if (__builtin_expect(fast, 1)) {
                const int r00 = (a0 * TJ + b0) * TK;
                const int r01 = (a0 * TJ + b1) * TK;
                const int r10 = (a1 * TJ + b0) * TK;
                const int r11 = (a1 * TJ + b1) * TK;
                atomicAdd(&tile[r00 + c0], v000);
                atomicAdd(&tile[r00 + c1], v001);
                atomicAdd(&tile[r01 + c0], v010);
                atomicAdd(&tile[r01 + c1], v011);
                atomicAdd(&tile[r10 + c0], v100);
                atomicAdd(&tile[r10 + c1], v101);
                atomicAdd(&tile[r11 + c0], v110);
                atomicAdd(&tile[r11 + c1], v111);
            } else {
                // rare outlier: per-corner route to LDS or global
                const int   xs[2] = {x0, x1}, ys[2] = {y0, y1}, zs[2] = {z0, z1};
                const float vs[8] = {v000, v001, v010, v011, v100, v101, v110, v111};
#pragma unroll
                for (int c = 0; c < 8; ++c) {
                    const int xx = xs[(c >> 2) & 1], yy = ys[(c >> 1) & 1], zz = zs[c & 1];
                    const int ta = xx - xg0, tb = yy - yg0, tc = zz - zg0;
                    if (((unsigned)ta < (unsigned)TI) & ((unsigned)tb < (unsigned)TJ) &
                        ((unsigned)tc < (unsigned)TK)) {
                        atomicAdd(&tile[(ta * TJ + tb) * TK + tc], vs[c]);
                    } else {
                        unsafeAtomicAdd(out + xx * WD + yy * Dd + zz, vs[c]);
                    }
                }
            }
        }
    }
    __syncthreads();

    // --- flush: 18432 cells / 512 threads = 36 each, coalesced, skip zeros ---
#pragma unroll
    for (int r = 0; r < TCELLS / 512; ++r) {
        const int c = t + 512 * r;
        const float v = tile[c];
        if (v != 0.0f) {
            const int tk = c % TK;
            const int rest = c / TK;
            const int tj = rest % TJ;
            const int ti = rest / TJ;
            const int x = xg0 + ti, y = yg0 + tj, z = zg0 + tk;
            if (((unsigned)x < (unsigned)H) & ((unsigned)y < (unsigned)W) &
                ((unsigned)z < (unsigned)Dd)) {
                unsafeAtomicAdd(out + x * WD + y * Dd + z, v);
            }
        }
    }
}

extern "C" void kernel_launch(void* const* d_in, const int* in_sizes, int n_in,
                              void* d_out, int out_size, void* d_ws, size_t ws_size,
                              hipStream_t stream) {
    const float* src  = (const float*)d_in[0];
    const float* flow = (const float*)d_in[1];
    float* out = (float*)d_out;

    // Harness poisons d_out once and never re-poisons between replays: zero it every call.
    hipMemsetAsync(out, 0, (size_t)N * sizeof(float), stream);

    const dim3 block(512);
    const dim3 grid(Dd / BK, W / BJ, H / BI);  // (3, 24, 24) = 1728 blocks
    splat_lds_kernel<<<grid, block, 0, stream>>>(src, flow, out);
}

// Round 4
// 308.527 us; speedup vs baseline: 9.1736x; 1.0261x over previous
//
#include <hip/hip_runtime.h>

// Trilinear forward-splat with per-block LDS tile accumulation.
// Reference semantics (exact):
//   locs = max(grid + flow, 0)
//   delta = locs - floor(locs)           (from UNclamped floor)
//   base  = min((int)floor(locs), dim-1)
//   corner per axis = min(base + {0,1}, dim-1)   (collapsed corners add twice)
//
// Round 3 -> 4 change: halo 4 -> 2. Tile 12x12x68 = 38.25 KB -> 4 blocks/CU
// (was 2), targeting 100% occupancy (kernel is latency-bound: VALUBusy 8.8%,
// hbm 2-5%, occupancy 43.6%). Slow-path rate ~1.2% of voxels (face voxels with
// |flow|>2); per-corner fallback keeps in-tile corners in LDS.

constexpr int H = 192, W = 192, Dd = 192;
constexpr int N = H * W * Dd;
constexpr int WD = W * Dd;

constexpr int BI = 8, BJ = 8, BK = 64;       // source chunk per block
constexpr int HL = 2;                        // halo radius
constexpr int TI = BI + 2 * HL;              // 12
constexpr int TJ = BJ + 2 * HL;              // 12
constexpr int TK = BK + 2 * HL;              // 68
constexpr int TCELLS = TI * TJ * TK;         // 9792 floats = 38.25 KB

// 512 threads (8 waves); want 4 blocks/CU = 32 waves/CU = 8 waves/SIMD.
__global__ __launch_bounds__(512, 8) void splat_lds_kernel(const float* __restrict__ src,
                                                           const float* __restrict__ flow,
                                                           float* __restrict__ out) {
    __shared__ __align__(16) float tile[TCELLS];

    const int t  = threadIdx.x;
    const int bk = blockIdx.x, bj = blockIdx.y, bi = blockIdx.z;
    const int i0 = bi * BI, j0 = bj * BJ, k0 = bk * BK;
    const int xg0 = i0 - HL, yg0 = j0 - HL, zg0 = k0 - HL;  // tile origin (global)

    // --- zero the tile (2448 float4 / 512 threads) ---
    {
        const float4 z4 = make_float4(0.f, 0.f, 0.f, 0.f);
        float4* t4 = reinterpret_cast<float4*>(tile);
        for (int c = t; c < TCELLS / 4; c += 512) t4[c] = z4;
    }
    __syncthreads();

    // --- scatter: 4096 voxels / block, 4 consecutive-k voxels per thread-pass ---
#pragma unroll
    for (int p = 0; p < 2; ++p) {
        const int g  = p * 512 + t;            // float4-group index, 0..1023
        const int kg = (g & 15) * 4;           // 0..60
        const int cj = (g >> 4) & 7;
        const int ci = g >> 7;                 // 0..7
        const int i = i0 + ci, j = j0 + cj, k = k0 + kg;
        const int off = i * WD + j * Dd + k;

        const float4 s4  = *reinterpret_cast<const float4*>(src + off);
        const float4 fx4 = *reinterpret_cast<const float4*>(flow + off);
        const float4 fy4 = *reinterpret_cast<const float4*>(flow + N + off);
        const float4 fz4 = *reinterpret_cast<const float4*>(flow + 2 * N + off);

        const float sa[4]  = {s4.x, s4.y, s4.z, s4.w};
        const float fxa[4] = {fx4.x, fx4.y, fx4.z, fx4.w};
        const float fya[4] = {fy4.x, fy4.y, fy4.z, fy4.w};
        const float fza[4] = {fz4.x, fz4.y, fz4.z, fz4.w};

#pragma unroll
        for (int q = 0; q < 4; ++q) {
            const float lx = fmaxf((float)i       + fxa[q], 0.0f);
            const float ly = fmaxf((float)j       + fya[q], 0.0f);
            const float lz = fmaxf((float)(k + q) + fza[q], 0.0f);

            const float bx = floorf(lx), by = floorf(ly), bz = floorf(lz);
            const float dx = lx - bx,    dy = ly - by,    dz = lz - bz;

            const int x0 = min((int)bx, H - 1);
            const int y0 = min((int)by, W - 1);
            const int z0 = min((int)bz, Dd - 1);
            const int x1 = min(x0 + 1, H - 1);
            const int y1 = min(y0 + 1, W - 1);
            const int z1 = min(z0 + 1, Dd - 1);

            const float s = sa[q];
            const float wx0 = 1.0f - dx, wy0 = 1.0f - dy, wz0 = 1.0f - dz;
            const float a00 = s * wx0 * wy0;
            const float a01 = s * wx0 * dy;
            const float a10 = s * dx * wy0;
            const float a11 = s * dx * dy;

            const float v000 = a00 * wz0, v001 = a00 * dz;
            const float v010 = a01 * wz0, v011 = a01 * dz;
            const float v100 = a10 * wz0, v101 = a10 * dz;
            const float v110 = a11 * wz0, v111 = a11 * dz;

            // tile-local coords
            const int a0 = x0 - xg0, a1 = x1 - xg0;
            const int b0 = y0 - yg0, b1 = y1 - yg0;
            const int c0 = z0 - zg0, c1 = z1 - zg0;

            const bool fast = ((unsigned)a0 < (unsigned)TI) & ((unsigned)a1 < (unsigned)TI) &
                              ((unsigned)b0 < (unsigned)TJ) & ((unsigned)b1 < (unsigned)TJ) &
                              ((unsigned)c0 < (unsigned)TK) & ((unsigned)c1 < (unsigned)TK);

            if (__builtin_expect(fast, 1)) {
                const int r00 = (a0 * TJ + b0) * TK;
                const int r01 = (a0 * TJ + b1) * TK;
                const int r10 = (a1 * TJ + b0) * TK;
                const int r11 = (a1 * TJ + b1) * TK;
                atomicAdd(&tile[r00 + c0], v000);
                atomicAdd(&tile[r00 + c1], v001);
                atomicAdd(&tile[r01 + c0], v010);
                atomicAdd(&tile[r01 + c1], v011);
                atomicAdd(&tile[r10 + c0], v100);
                atomicAdd(&tile[r10 + c1], v101);
                atomicAdd(&tile[r11 + c0], v110);
                atomicAdd(&tile[r11 + c1], v111);
            } else {
                // rare: per-corner route to LDS (if in tile) or global
                const int   xs[2] = {x0, x1}, ys[2] = {y0, y1}, zs[2] = {z0, z1};
                const float vs[8] = {v000, v001, v010, v011, v100, v101, v110, v111};
#pragma unroll
                for (int c = 0; c < 8; ++c) {
                    const int xx = xs[(c >> 2) & 1], yy = ys[(c >> 1) & 1], zz = zs[c & 1];
                    const int ta = xx - xg0, tb = yy - yg0, tc = zz - zg0;
                    if (((unsigned)ta < (unsigned)TI) & ((unsigned)tb < (unsigned)TJ) &
                        ((unsigned)tc < (unsigned)TK)) {
                        atomicAdd(&tile[(ta * TJ + tb) * TK + tc], vs[c]);
                    } else {
                        unsafeAtomicAdd(out + xx * WD + yy * Dd + zz, vs[c]);
                    }
                }
            }
        }
    }
    __syncthreads();

    // --- flush: coalesced along z, one global atomic per nonzero cell ---
    for (int c = t; c < TCELLS; c += 512) {
        const float v = tile[c];
        if (v != 0.0f) {
            const int tk = c % TK;
            const int rest = c / TK;
            const int tj = rest % TJ;
            const int ti = rest / TJ;
            const int x = xg0 + ti, y = yg0 + tj, z = zg0 + tk;
            if (((unsigned)x < (unsigned)H) & ((unsigned)y < (unsigned)W) &
                ((unsigned)z < (unsigned)Dd)) {
                unsafeAtomicAdd(out + x * WD + y * Dd + z, v);
            }
        }
    }
}

extern "C" void kernel_launch(void* const* d_in, const int* in_sizes, int n_in,
                              void* d_out, int out_size, void* d_ws, size_t ws_size,
                              hipStream_t stream) {
    const float* src  = (const float*)d_in[0];
    const float* flow = (const float*)d_in[1];
    float* out = (float*)d_out;

    // Harness poisons d_out once and never re-poisons between replays: zero it every call.
    hipMemsetAsync(out, 0, (size_t)N * sizeof(float), stream);

    const dim3 block(512);
    const dim3 grid(Dd / BK, W / BJ, H / BI);  // (3, 24, 24) = 1728 blocks
    splat_lds_kernel<<<grid, block, 0, stream>>>(src, flow, out);
}